// Round 16
// baseline (561.044 us; speedup 1.0000x reference)
//
#include <hip/hip_runtime.h>

#define V_SIZE 32000
#define D_DIM  1024
#define H_HEADS 16
#define L_LAYERS 4
#define HD_DIM 64
#define FF_DIM 4096
#define B_BATCH 2
#define S_SEQ  1024
#define M_ROWS (B_BATCH*S_SEQ)
#define KSPL   2

typedef short  s16x8 __attribute__((ext_vector_type(8)));
typedef unsigned short u16x8 __attribute__((ext_vector_type(8)));
typedef float  f32x4 __attribute__((ext_vector_type(4)));
typedef unsigned short u16;
typedef unsigned int   u32;

// f32 -> bf16 round-to-nearest-even
__device__ inline u16 f2bf(float f){
    u32 u = __float_as_uint(f);
    return (u16)((u + 0x7FFFu + ((u >> 16) & 1u)) >> 16);
}
__device__ inline float b2f(u32 v){ return __uint_as_float(v << 16); }

// fast exact-enough GELU: sigmoid form; |err| <= ~4e-4
__device__ inline float gelu_f(float v){
    float y = 0.7978845608f * (v + 0.044715f*v*v*v);
    y = fmaxf(-15.f, fminf(15.f, y));
    float u = __expf(-2.f*y);
    return v / (1.f + u);
}

// Swizzled LDS address for 128-byte rows (64 bf16): byte ^= ((row&7)<<4)  [guide G4]
__device__ inline char* lds_swz(void* base, int row, int byteoff){
    return (char*)base + row*128 + (byteoff ^ ((row & 7) << 4));
}

// async global->LDS, 16B per lane. LDS dest must be linear-in-lane. [guide §5]
__device__ inline void gload16(const u16* g, u16* l){
    __builtin_amdgcn_global_load_lds(
        (const __attribute__((address_space(1))) void*)g,
        (__attribute__((address_space(3))) void*)l, 16, 0, 0);
}

// Matching global source column for swizzled LDS slot 'lin' (16B granules):
__device__ inline int swz_src_col(int lin){
    int row = lin >> 3, s8 = lin & 7;
    return (s8*8) ^ ((row & 7) << 3);
}

__device__ inline s16x8 cvt8v(f32x4 a, f32x4 b){
    s16x8 o;
    o[0]=(short)f2bf(a.x); o[1]=(short)f2bf(a.y);
    o[2]=(short)f2bf(a.z); o[3]=(short)f2bf(a.w);
    o[4]=(short)f2bf(b.x); o[5]=(short)f2bf(b.y);
    o[6]=(short)f2bf(b.z); o[7]=(short)f2bf(b.w);
    return o;
}

// ---------------------------------------------------------------------------
// All weight converts in ONE dispatch. NON-TEMPORAL loads+stores (ext-vector
// types, which the builtin accepts): sources read-once, dests
// write-once-read-much-later -> bypass L2/L3 allocation. r14 PMC: FETCH only
// 98MB of 192MB source, HBM 2.3 TB/s unsaturated -> cache-path contention.
// ---------------------------------------------------------------------------
__global__ __launch_bounds__(256) void cvt_all_k(
    const float* __restrict__ qw, const float* __restrict__ kw,
    const float* __restrict__ vw, const float* __restrict__ ow,
    const float* __restrict__ f1w, const float* __restrict__ f2w,
    u16* __restrict__ w_qkv, u16* __restrict__ w_o,
    u16* __restrict__ w_f1, u16* __restrict__ w_f2)
{
    const long M1 = 1L << 20;
    const int bx = blockIdx.x;
    const float* s; u16* d; long base;
    if (bx < 3072){
        int which = bx >> 10;
        s = (which==0) ? qw : ((which==1) ? kw : vw);
        base = (long)(bx & 1023) * 4096;
        long layer = base >> 20, rem = base & (M1 - 1);
        d = w_qkv + layer*3*M1 + which*M1 + rem;
        s += base;
    } else if (bx < 4096){
        base = (long)(bx - 3072) * 4096; s = ow  + base; d = w_o  + base;
    } else if (bx < 8192){
        base = (long)(bx - 4096) * 4096; s = f1w + base; d = w_f1 + base;
    } else {
        base = (long)(bx - 8192) * 4096; s = f2w + base; d = w_f2 + base;
    }
    const int t8 = threadIdx.x * 8;
#pragma unroll
    for (int j = 0; j < 2; j++){
        const f32x4* sp = (const f32x4*)(s + j*2048 + t8);
        f32x4 v0 = __builtin_nontemporal_load(sp);
        f32x4 v1 = __builtin_nontemporal_load(sp + 1);
        s16x8 o = cvt8v(v0, v1);
        __builtin_nontemporal_store(o, (s16x8*)(d + j*2048 + t8));
    }
}

// ---------------------------------------------------------------------------
// Embedding + LN1(layer0): block = one row.
// ---------------------------------------------------------------------------
__global__ __launch_bounds__(256) void embed_ln_k(
    const int* __restrict__ ids, const float* __restrict__ tok,
    const float* __restrict__ pos, const float* __restrict__ lw,
    const float* __restrict__ lb, float* __restrict__ x, u16* __restrict__ h)
{
    int row = blockIdx.x;
    int id  = ids[row];
    int s   = row & (S_SEQ - 1);
    int t   = threadIdx.x;
    float4 tv = *(const float4*)(tok + (size_t)id * D_DIM + t*4);
    float4 pv = *(const float4*)(pos + (size_t)s  * D_DIM + t*4);
    float4 vv;
    vv.x = tv.x + pv.x; vv.y = tv.y + pv.y; vv.z = tv.z + pv.z; vv.w = tv.w + pv.w;
    *(float4*)(x + (size_t)row * D_DIM + t*4) = vv;
    float sm  = vv.x + vv.y + vv.z + vv.w;
    float ss = vv.x*vv.x + vv.y*vv.y + vv.z*vv.z + vv.w*vv.w;
#pragma unroll
    for (int off = 1; off < 64; off <<= 1){
        sm += __shfl_xor(sm, off);
        ss += __shfl_xor(ss, off);
    }
    __shared__ float red[8];
    const int wid = t >> 6, lane = t & 63;
    if (lane == 0){ red[wid] = sm; red[4 + wid] = ss; }
    __syncthreads();
    sm = red[0] + red[1] + red[2] + red[3];
    ss = red[4] + red[5] + red[6] + red[7];
    float mu   = sm * (1.0f/1024.0f);
    float rstd = rsqrtf(ss * (1.0f/1024.0f) - mu*mu + 1e-5f);
    float4 wv = *(const float4*)(lw + t*4);
    float4 bv = *(const float4*)(lb + t*4);
    uint2 pk;
    pk.x = (u32)f2bf((vv.x-mu)*rstd*wv.x + bv.x) | ((u32)f2bf((vv.y-mu)*rstd*wv.y + bv.y) << 16);
    pk.y = (u32)f2bf((vv.z-mu)*rstd*wv.z + bv.z) | ((u32)f2bf((vv.w-mu)*rstd*wv.w + bv.w) << 16);
    *(uint2*)(h + (size_t)row * D_DIM + t*4) = pk;
}

// ---------------------------------------------------------------------------
// Split-K reduce (bf16 partials) + residual + fused LN. Block = row.
// ---------------------------------------------------------------------------
__global__ __launch_bounds__(256) void reduce_ln_k(
    const u16* __restrict__ part, const float* __restrict__ bias,
    float* __restrict__ x,
    const float* __restrict__ lw, const float* __restrict__ lb,
    u16* __restrict__ h)
{
    const int row = blockIdx.x, t = threadIdx.x;
    const size_t off = (size_t)row * D_DIM + t*4;
    float4 a = *(float4*)(x + off);
    float4 bv = *(const float4*)(bias + t*4);
    a.x += bv.x; a.y += bv.y; a.z += bv.z; a.w += bv.w;
#pragma unroll
    for (int si = 0; si < KSPL; si++){
        uint2 pv = *(const uint2*)(part + (size_t)si * M_ROWS * D_DIM + off);
        a.x += b2f(pv.x & 0xffffu); a.y += b2f(pv.x >> 16);
        a.z += b2f(pv.y & 0xffffu); a.w += b2f(pv.y >> 16);
    }
    *(float4*)(x + off) = a;
    float sm = a.x + a.y + a.z + a.w;
    float ss = a.x*a.x + a.y*a.y + a.z*a.z + a.w*a.w;
#pragma unroll
    for (int o2 = 1; o2 < 64; o2 <<= 1){
        sm += __shfl_xor(sm, o2);
        ss += __shfl_xor(ss, o2);
    }
    __shared__ float red[8];
    const int wid = t >> 6, lane = t & 63;
    if (lane == 0){ red[wid] = sm; red[4 + wid] = ss; }
    __syncthreads();
    sm = red[0] + red[1] + red[2] + red[3];
    ss = red[4] + red[5] + red[6] + red[7];
    float mu   = sm * (1.0f/1024.0f);
    float rstd = rsqrtf(ss * (1.0f/1024.0f) - mu*mu + 1e-5f);
    float4 wv = *(const float4*)(lw + t*4);
    float4 lbv = *(const float4*)(lb + t*4);
    uint2 pk;
    pk.x = (u32)f2bf((a.x-mu)*rstd*wv.x + lbv.x) | ((u32)f2bf((a.y-mu)*rstd*wv.y + lbv.y) << 16);
    pk.y = (u32)f2bf((a.z-mu)*rstd*wv.z + lbv.z) | ((u32)f2bf((a.w-mu)*rstd*wv.w + lbv.w) << 16);
    *(uint2*)(h + (size_t)row * D_DIM + t*4) = pk;
}

// ---------------------------------------------------------------------------
// fc1 GEMM: 128x128 tile, bias + gelu -> bf16. grid (16,32), 2 blocks/CU.
// ---------------------------------------------------------------------------
__global__ __launch_bounds__(256) void gemm_fc1_k(
    const u16* __restrict__ A, const u16* __restrict__ Bw,
    const float* __restrict__ b0, u16* __restrict__ outB, int Ndim, int Kdim)
{
    const int nx = gridDim.x, ny = gridDim.y;
    const int nwg = nx*ny;
    int orig = blockIdx.y*nx + blockIdx.x;
    int wg = (orig & 7)*(nwg >> 3) + (orig >> 3);
    const int bm = wg % nx;
    const int bn = wg / nx;

    const int nk = Kdim >> 6;

    __shared__ __align__(16) u16 As[2][128*64];
    __shared__ __align__(16) u16 Bs[2][128*64];

    const int t = threadIdx.x;
    const int wid = t >> 6, lane = t & 63, lr = lane & 15, lg = lane >> 4;
    const int wr = wid >> 1, wc = wid & 1;

    f32x4 acc[4][4];
#pragma unroll
    for (int m=0;m<4;m++)
#pragma unroll
        for (int n=0;n<4;n++) acc[m][n] = (f32x4){0.f,0.f,0.f,0.f};

    const u16* Abase = A  + (size_t)(bm*128)*Kdim;
    const u16* Bbase = Bw + (size_t)(bn*128)*Kdim;

    auto stage = [&](int koff, int buf){
#pragma unroll
        for (int i=0;i<4;i++){
            int lin = i*256 + t;
            int row = lin >> 3;
            int sc  = swz_src_col(lin);
            gload16(Abase + (size_t)row*Kdim + koff + sc, &As[buf][lin*8]);
        }
#pragma unroll
        for (int i=0;i<4;i++){
            int lin = i*256 + t;
            int row = lin >> 3;
            int sc  = swz_src_col(lin);
            gload16(Bbase + (size_t)row*Kdim + koff + sc, &Bs[buf][lin*8]);
        }
    };

    stage(0, 0);
    __syncthreads();
    int cb = 0;
    for (int ki = 0; ki < nk; ki++){
        if (ki+1 < nk) stage((ki+1)*64, cb^1);
#pragma unroll
        for (int kk=0;kk<2;kk++){
            s16x8 a[4], b[4];
#pragma unroll
            for (int m=0;m<4;m++)
                a[m] = *(s16x8*)lds_swz(As[cb], wr*64 + m*16 + lr, kk*64 + lg*16);
#pragma unroll
            for (int n=0;n<4;n++)
                b[n] = *(s16x8*)lds_swz(Bs[cb], wc*64 + n*16 + lr, kk*64 + lg*16);
#pragma unroll
            for (int m=0;m<4;m++)
#pragma unroll
                for (int n=0;n<4;n++)
                    acc[m][n] = __builtin_amdgcn_mfma_f32_16x16x32_bf16(a[m], b[n], acc[m][n], 0, 0, 0);
        }
        __syncthreads();
        cb ^= 1;
    }

#pragma unroll
    for (int n=0;n<4;n++){
        int col = bn*128 + wc*64 + n*16 + lr;
        float bvv = b0[col];
#pragma unroll
        for (int m=0;m<4;m++){
            int row0 = bm*128 + wr*64 + m*16 + lg*4;
#pragma unroll
            for (int j=0;j<4;j++){
                int row = row0 + j;
                float val = gelu_f(acc[m][n][j] + bvv);
                outB[(size_t)row * Ndim + col] = f2bf(val);
            }
        }
    }
}

// ---------------------------------------------------------------------------
// Output GEMM, 64x128 tile: C = A @ Bw^T + bias -> bf16.
// Segmented bias (col>>10 -> b0/b1/b2), segment QSEG scaled 0.125.
// ---------------------------------------------------------------------------
template<int QSEG>
__global__ __launch_bounds__(256) void gemm64o_k(
    const u16* __restrict__ A, const u16* __restrict__ Bw,
    const float* __restrict__ b0, const float* __restrict__ b1, const float* __restrict__ b2,
    u16* __restrict__ outB, int Ndim, int Kdim)
{
    const int nx = gridDim.x, ny = gridDim.y;
    const int nwg = nx*ny;
    int orig = blockIdx.y*nx + blockIdx.x;
    int wg = (orig & 7)*(nwg >> 3) + (orig >> 3);
    const int bm = wg % nx;
    const int bn = wg / nx;
    const int nk = Kdim >> 6;

    __shared__ __align__(16) u16 As[2][64*64];
    __shared__ __align__(16) u16 Bs[2][128*64];

    const int t = threadIdx.x;
    const int wid = t >> 6, lane = t & 63, lr = lane & 15, lg = lane >> 4;
    const int wr = wid >> 1, wc = wid & 1;

    f32x4 acc[2][4];
#pragma unroll
    for (int m=0;m<2;m++)
#pragma unroll
        for (int n=0;n<4;n++) acc[m][n] = (f32x4){0.f,0.f,0.f,0.f};

    const u16* Abase = A  + (size_t)(bm*64)*Kdim;
    const u16* Bbase = Bw + (size_t)(bn*128)*Kdim;

    auto stage = [&](int koff, int buf){
#pragma unroll
        for (int i=0;i<2;i++){
            int lin = i*256 + t;
            int row = lin >> 3;
            int sc  = swz_src_col(lin);
            gload16(Abase + (size_t)row*Kdim + koff + sc, &As[buf][lin*8]);
        }
#pragma unroll
        for (int i=0;i<4;i++){
            int lin = i*256 + t;
            int row = lin >> 3;
            int sc  = swz_src_col(lin);
            gload16(Bbase + (size_t)row*Kdim + koff + sc, &Bs[buf][lin*8]);
        }
    };

    stage(0, 0);
    __syncthreads();
    int cb = 0;
    for (int ki = 0; ki < nk; ki++){
        if (ki+1 < nk) stage((ki+1)*64, cb^1);
#pragma unroll
        for (int kk=0;kk<2;kk++){
            s16x8 a[2], b[4];
#pragma unroll
            for (int m=0;m<2;m++)
                a[m] = *(s16x8*)lds_swz(As[cb], wr*32 + m*16 + lr, kk*64 + lg*16);
#pragma unroll
            for (int n=0;n<4;n++)
                b[n] = *(s16x8*)lds_swz(Bs[cb], wc*64 + n*16 + lr, kk*64 + lg*16);
#pragma unroll
            for (int m=0;m<2;m++)
#pragma unroll
                for (int n=0;n<4;n++)
                    acc[m][n] = __builtin_amdgcn_mfma_f32_16x16x32_bf16(a[m], b[n], acc[m][n], 0, 0, 0);
        }
        __syncthreads();
        cb ^= 1;
    }

#pragma unroll
    for (int n=0;n<4;n++){
        int col = bn*128 + wc*64 + n*16 + lr;
        int which = col >> 10;
        const float* bp = (which==0) ? b0 : ((which==1) ? b1 : b2);
        float bvv = bp[col & 1023];
        float scl = (which == QSEG) ? 0.125f : 1.0f;
#pragma unroll
        for (int m=0;m<2;m++){
            int row0 = bm*64 + wr*32 + m*16 + lg*4;
#pragma unroll
            for (int j=0;j<4;j++){
                int row = row0 + j;
                float val = (acc[m][n][j] + bvv) * scl;
                outB[(size_t)row * Ndim + col] = f2bf(val);
            }
        }
    }
}

// ---------------------------------------------------------------------------
// Split-K GEMM, 64x128 tile: part[z] = A[M,K] @ Bw[N,K]^T  (K-slice z), bf16 out.
// ---------------------------------------------------------------------------
__global__ __launch_bounds__(256) void gemm64_k(
    const u16* __restrict__ A, const u16* __restrict__ Bw,
    u16* __restrict__ outP, int Ndim, int Kdim, int kper)
{
    const int nx = gridDim.x, ny = gridDim.y;
    const int nwg = nx*ny*gridDim.z;
    int orig = (blockIdx.z*ny + blockIdx.y)*nx + blockIdx.x;
    int wg = (orig & 7)*(nwg >> 3) + (orig >> 3);
    const int bm = wg % nx; wg /= nx;
    const int bn = wg % ny;
    const int z  = wg / ny;
    const int kbeg = z * kper;
    const int nk = kper >> 6;

    __shared__ __align__(16) u16 As[2][64*64];
    __shared__ __align__(16) u16 Bs[2][128*64];

    const int t = threadIdx.x;
    const int wid = t >> 6, lane = t & 63, lr = lane & 15, lg = lane >> 4;
    const int wr = wid >> 1, wc = wid & 1;

    f32x4 acc[2][4];
#pragma unroll
    for (int m=0;m<2;m++)
#pragma unroll
        for (int n=0;n<4;n++) acc[m][n] = (f32x4){0.f,0.f,0.f,0.f};

    const u16* Abase = A  + (size_t)(bm*64)*Kdim + kbeg;
    const u16* Bbase = Bw + (size_t)(bn*128)*Kdim + kbeg;

    auto stage = [&](int koff, int buf){
#pragma unroll
        for (int i=0;i<2;i++){
            int lin = i*256 + t;
            int row = lin >> 3;
            int sc  = swz_src_col(lin);
            gload16(Abase + (size_t)row*Kdim + koff + sc, &As[buf][lin*8]);
        }
#pragma unroll
        for (int i=0;i<4;i++){
            int lin = i*256 + t;
            int row = lin >> 3;
            int sc  = swz_src_col(lin);
            gload16(Bbase + (size_t)row*Kdim + koff + sc, &Bs[buf][lin*8]);
        }
    };

    stage(0, 0);
    __syncthreads();
    int cb = 0;
    for (int ki = 0; ki < nk; ki++){
        if (ki+1 < nk) stage((ki+1)*64, cb^1);
#pragma unroll
        for (int kk=0;kk<2;kk++){
            s16x8 a[2], b[4];
#pragma unroll
            for (int m=0;m<2;m++)
                a[m] = *(s16x8*)lds_swz(As[cb], wr*32 + m*16 + lr, kk*64 + lg*16);
#pragma unroll
            for (int n=0;n<4;n++)
                b[n] = *(s16x8*)lds_swz(Bs[cb], wc*64 + n*16 + lr, kk*64 + lg*16);
#pragma unroll
            for (int m=0;m<2;m++)
#pragma unroll
                for (int n=0;n<4;n++)
                    acc[m][n] = __builtin_amdgcn_mfma_f32_16x16x32_bf16(a[m], b[n], acc[m][n], 0, 0, 0);
        }
        __syncthreads();
        cb ^= 1;
    }

#pragma unroll
    for (int n=0;n<4;n++){
        int col = bn*128 + wc*64 + n*16 + lr;
#pragma unroll
        for (int m=0;m<2;m++){
            int row0 = bm*64 + wr*32 + m*16 + lg*4;
#pragma unroll
            for (int j=0;j<4;j++){
                int row = row0 + j;
                outP[(size_t)z * M_ROWS * Ndim + (size_t)row * Ndim + col] = f2bf(acc[m][n][j]);
            }
        }
    }
}

// ---------------------------------------------------------------------------
// Flash attention, causal, paired strips SHARING K/V tiles, 8 WAVES (512 thr).
// grid (8, B*H) = 256 blocks; waves 0-3: strip_lo, waves 4-7: strip_hi.
// ---------------------------------------------------------------------------
__global__ __launch_bounds__(512) void attn_k(
    const u16* __restrict__ qkv, u16* __restrict__ y)
{
    const int gx = gridDim.x;
    const int nwg = gx * gridDim.y;
    int orig = blockIdx.y*gx + blockIdx.x;
    int wg = (orig & 7)*(nwg >> 3) + (orig >> 3);
    const int p  = wg % gx;
    const int bh = wg / gx;
    const int b  = bh >> 4, h = bh & 15;

    const int s_lo = p, s_hi = 15 - p;
    const int ntiles = s_hi + 1;

    __shared__ __align__(16) u16 Ks[2][64*64];
    __shared__ __align__(16) u16 VTs[2][64*64];
    __shared__ __align__(16) u16 Ps[8][16*64];

    const int t = threadIdx.x, wid = t >> 6, lane = t & 63, lr = lane & 15, lg = lane >> 4;
    const size_t rowb = (size_t)b * S_SEQ;
    const u16* qp = qkv + h*HD_DIM;
    const u16* kp = qkv + 1024 + h*HD_DIM;
    const u16* vp = qkv + 2048 + h*HD_DIM;

    const int s  = (wid >= 4) ? s_hi : s_lo;
    const int wq = wid & 3;
    const int qw = s*64 + wq*16;

    s16x8 aq[2];
#pragma unroll
    for (int kc=0;kc<2;kc++)
        aq[kc] = *(const s16x8*)(qp + (rowb + qw + lr) * 3072 + kc*32 + lg*8);

    f32x4 o[4];
#pragma unroll
    for (int n=0;n<4;n++) o[n] = (f32x4){0.f,0.f,0.f,0.f};
    float lsum[4] = {0.f,0.f,0.f,0.f};

    const int kpr = t >> 3, dsl = t & 7;
    u16x8 vr0, vr1;

    auto issueK = [&](int kt, int buf){
        if (t >= 256){
#pragma unroll
            for (int i=0;i<2;i++){
                int lin = i*256 + (t - 256);
                int row = lin >> 3;
                int sc  = swz_src_col(lin);
                gload16(kp + (rowb + kt*64 + row)*3072 + sc, &Ks[buf][lin*8]);
            }
        }
    };
    auto loadV = [&](int kt){
        if (t < 256){
            vr0 = *(const u16x8*)(vp + (rowb + kt*64 + 2*kpr    )*3072 + dsl*8);
            vr1 = *(const u16x8*)(vp + (rowb + kt*64 + 2*kpr + 1)*3072 + dsl*8);
        }
    };
    auto writeVT = [&](int buf){
        if (t < 256){
#pragma unroll
            for (int j=0;j<8;j++){
                u32 pk = (u32)vr0[j] | ((u32)vr1[j] << 16);
                *(u32*)lds_swz(VTs[buf], dsl*8 + j, kpr*4) = pk;
            }
        }
    };

    auto doTile = [&](int kt, int cb){
        f32x4 sf[4];
#pragma unroll
        for (int n=0;n<4;n++) sf[n] = (f32x4){0.f,0.f,0.f,0.f};
        __builtin_amdgcn_s_setprio(1);
#pragma unroll
        for (int kc=0;kc<2;kc++){
#pragma unroll
            for (int n=0;n<4;n++){
                s16x8 bk = *(s16x8*)lds_swz(Ks[cb], n*16 + lr, kc*64 + lg*16);
                sf[n] = __builtin_amdgcn_mfma_f32_16x16x32_bf16(aq[kc], bk, sf[n], 0, 0, 0);
            }
        }
        __builtin_amdgcn_s_setprio(0);
        const bool diag = (kt == s);
        float rs[4] = {0.f,0.f,0.f,0.f};
#pragma unroll
        for (int n=0;n<4;n++){
            int key = kt*64 + n*16 + lr;
#pragma unroll
            for (int j=0;j<4;j++){
                float pe = __expf(sf[n][j]);
                if (diag && key > qw + lg*4 + j) pe = 0.f;
                sf[n][j] = pe; rs[j] += pe;
            }
        }
#pragma unroll
        for (int off=1; off<16; off<<=1){
#pragma unroll
            for (int j=0;j<4;j++) rs[j] += __shfl_xor(rs[j], off);
        }
#pragma unroll
        for (int j=0;j<4;j++) lsum[j] += rs[j];
        u16* Pw = Ps[wid];
#pragma unroll
        for (int n=0;n<4;n++)
#pragma unroll
            for (int j=0;j<4;j++)
                *(u16*)lds_swz(Pw, lg*4 + j, (n*16 + lr)*2) = f2bf(sf[n][j]);
        __builtin_amdgcn_s_setprio(1);
#pragma unroll
        for (int kc=0;kc<2;kc++){
            s16x8 pa = *(s16x8*)lds_swz(Pw, lr, kc*64 + lg*16);
#pragma unroll
            for (int n=0;n<4;n++){
                s16x8 bv = *(s16x8*)lds_swz(VTs[cb], n*16 + lr, kc*64 + lg*16);
                o[n] = __builtin_amdgcn_mfma_f32_16x16x32_bf16(pa, bv, o[n], 0, 0, 0);
            }
        }
        __builtin_amdgcn_s_setprio(0);
    };

    issueK(0, 0); loadV(0); writeVT(0);
    __syncthreads();
    int cb = 0;
    for (int kt = 0; kt < ntiles; kt++){
        const bool more = (kt+1 < ntiles);
        if (more){ issueK(kt+1, cb^1); loadV(kt+1); }

        if (kt <= s) doTile(kt, cb);

        if (more) writeVT(cb^1);
        __syncthreads();
        cb ^= 1;
    }

    float inv[4];
#pragma unroll
    for (int j=0;j<4;j++) inv[j] = 1.0f / lsum[j];
#pragma unroll
    for (int n=0;n<4;n++)
#pragma unroll
        for (int j=0;j<4;j++)
            y[(rowb + qw + lg*4 + j) * D_DIM + h*HD_DIM + n*16 + lr] = f2bf(o[n][j] * inv[j]);
}

// ---------------------------------------------------------------------------
// Last-layer attention: q-rows {1023,2047} only. kv: [B*S][2048] (k|v).
// ---------------------------------------------------------------------------
__global__ __launch_bounds__(256) void attn_last_k(
    const u16* __restrict__ q2, const u16* __restrict__ kv,
    float* __restrict__ Yp, float* __restrict__ psp)
{
    const int chunk = blockIdx.x;
    const int bh = blockIdx.y;
    const int b = bh >> 4, h = bh & 15;
    const int t = threadIdx.x;
    const size_t rowb = (size_t)b * S_SEQ;
    __shared__ float qs[64];
    __shared__ float ps[256];
    __shared__ float red[4];
    __shared__ float yred[4][64];
    if (t < 64) qs[t] = b2f(q2[b*1024 + h*HD_DIM + t]);
    __syncthreads();
    int k = chunk*256 + t;
    const u16* krow = kv + (rowb + k)*2048 + h*HD_DIM;
    float s = 0.f;
#pragma unroll
    for (int j=0;j<8;j++){
        u16x8 kv8 = *(const u16x8*)(krow + j*8);
#pragma unroll
        for (int e=0;e<8;e++) s += qs[j*8+e] * b2f((u32)(unsigned short)kv8[e]);
    }
    float p = __expf(s);
    ps[t] = p;
    float sp_ = p;
#pragma unroll
    for (int off=1; off<64; off<<=1) sp_ += __shfl_xor(sp_, off);
    if ((t & 63) == 0) red[t>>6] = sp_;
    __syncthreads();
    if (t == 0) psp[chunk*32 + bh] = red[0]+red[1]+red[2]+red[3];
    int d = t & 63, c = t >> 6;
    float acc = 0.f;
    const u16* vbase = kv + (rowb + chunk*256 + c*64)*2048 + 1024 + h*HD_DIM + d;
    for (int kk=0; kk<64; kk++)
        acc += ps[c*64 + kk] * b2f((u32)vbase[(size_t)kk*2048]);
    yred[c][d] = acc;
    __syncthreads();
    if (t < 64)
        Yp[(chunk*32 + bh)*64 + t] = yred[0][t]+yred[1][t]+yred[2][t]+yred[3][t];
}

// ---------------------------------------------------------------------------
// Two-row GEMM tail. grid = 256 blocks, 4 waves.
// ---------------------------------------------------------------------------
template<int MODE>
__global__ __launch_bounds__(256) void rowpair_k(
    const u16* __restrict__ A0, const u16* __restrict__ A1,
    const float* __restrict__ Yp, const float* __restrict__ psp,
    const float* __restrict__ x2in,
    const float* __restrict__ lw, const float* __restrict__ lb,
    const u16* __restrict__ W, const float* __restrict__ bias,
    const float* __restrict__ xresid,
    float* __restrict__ outF, u16* __restrict__ outB,
    int Ndim, int Kdim)
{
    __shared__ u16 As16[2][1024];
    __shared__ float red[8];
    const int t = threadIdx.x, wid = t >> 6, lane = t & 63;

    if (MODE == 0){
        for (int idx = t; idx < 2048; idx += 256){
            int r = idx >> 10, d10 = idx & 1023;
            int bh = r*16 + (d10 >> 6), d = d10 & 63;
            float psum = psp[bh] + psp[32+bh] + psp[64+bh] + psp[96+bh];
            float yv = Yp[bh*64+d] + Yp[(32+bh)*64+d] + Yp[(64+bh)*64+d] + Yp[(96+bh)*64+d];
            As16[r][d10] = f2bf(yv / psum);
        }
        __syncthreads();
    }
    if (MODE == 1){
#pragma unroll
        for (int r = 0; r < 2; r++){
            float4 vv = *(const float4*)(x2in + r*1024 + t*4);
            float sm = vv.x + vv.y + vv.z + vv.w;
            float ss = vv.x*vv.x + vv.y*vv.y + vv.z*vv.z + vv.w*vv.w;
#pragma unroll
            for (int o2 = 1; o2 < 64; o2 <<= 1){
                sm += __shfl_xor(sm, o2);
                ss += __shfl_xor(ss, o2);
            }
            if (lane == 0){ red[wid] = sm; red[4+wid] = ss; }
            __syncthreads();
            sm = red[0]+red[1]+red[2]+red[3];
            ss = red[4]+red[5]+red[6]+red[7];
            float mu = sm * (1.0f/1024.0f);
            float rstd = rsqrtf(ss * (1.0f/1024.0f) - mu*mu + 1e-5f);
            float4 wv  = *(const float4*)(lw + t*4);
            float4 lbv = *(const float4*)(lb + t*4);
            As16[r][t*4+0] = f2bf((vv.x-mu)*rstd*wv.x + lbv.x);
            As16[r][t*4+1] = f2bf((vv.y-mu)*rstd*wv.y + lbv.y);
            As16[r][t*4+2] = f2bf((vv.z-mu)*rstd*wv.z + lbv.z);
            As16[r][t*4+3] = f2bf((vv.w-mu)*rstd*wv.w + lbv.w);
            __syncthreads();
        }
    }

    const u16* pa0 = (MODE==0 || MODE==1) ? (const u16*)As16[0] : A0;
    const u16* pa1 = (MODE==0 || MODE==1) ? (const u16*)As16[1] : A1;

    const int colsPerBlock = Ndim >> 8;
    const int colsPerWave  = colsPerBlock >> 2;
    const int nj = Kdim >> 9;
    for (int cc = 0; cc < colsPerWave; cc++){
        int col = blockIdx.x * colsPerBlock + wid * colsPerWave + cc;
        const u16* wrow = W + (size_t)col * Kdim;
        float s0 = 0.f, s1 = 0.f;
        for (int j = 0; j < nj; j++){
            int k = j*512 + lane*8;
            u16x8 wv = *(const u16x8*)(wrow + k);
            u16x8 a0 = *(const u16x8*)(pa0 + k);
            u16x8 a1 = *(const u16x8*)(pa1 + k);
#pragma unroll
            for (int e=0;e<8;e++){
                float wf = b2f((u32)wv[e]);
                s0 += b2f((u32)a0[e]) * wf;
                s1 += b2f((u32)a1[e]) * wf;
            }
        }
#pragma unroll
        for (int off=1; off<64; off<<=1){
            s0 += __shfl_xor(s0, off);
            s1 += __shfl_xor(s1, off);
        }
        if (lane == 0){
            float bv = bias[col];
            if (MODE == 0){
                outF[col]         = xresid[(size_t)(S_SEQ-1)*D_DIM + col]   + bv + s0;
                outF[D_DIM + col] = xresid[(size_t)(2*S_SEQ-1)*D_DIM + col] + bv + s1;
            } else if (MODE == 1){
                outB[col]         = f2bf(gelu_f(s0 + bv));
                outB[Ndim + col]  = f2bf(gelu_f(s1 + bv));
            } else if (MODE == 2){
                outF[col]         = x2in[col]         + bv + s0;
                outF[D_DIM + col] = x2in[D_DIM + col] + bv + s1;
            } else {
                outB[col]         = f2bf((s0 + bv) * 0.125f);
                outB[Ndim + col]  = f2bf((s1 + bv) * 0.125f);
            }
        }
    }
}

// ---------------------------------------------------------------------------
// Head matvec with fused final LN: xs = LN(x3) per block, then dot rows.
// ---------------------------------------------------------------------------
__global__ __launch_bounds__(256) void head_ln_k(
    const float* __restrict__ x3, const float* __restrict__ w, const float* __restrict__ bb,
    const float* __restrict__ hw, float* __restrict__ out)
{
    __shared__ float xs[2*D_DIM];
    __shared__ float red[8];
    int t = threadIdx.x, wid = t >> 6, lane = t & 63;
#pragma unroll
    for (int r = 0; r < 2; r++){
        float4 vv = *(const float4*)(x3 + r*D_DIM + t*4);
        float s  = vv.x + vv.y + vv.z + vv.w;
        float ss = vv.x*vv.x + vv.y*vv.y + vv.z*vv.z + vv.w*vv.w;
#pragma unroll
        for (int off = 1; off < 64; off <<= 1){
            s  += __shfl_xor(s,  off);
            ss += __shfl_xor(ss, off);
        }
        if (lane == 0){ red[wid] = s; red[4+wid] = ss; }
        __syncthreads();
        s  = red[0]+red[1]+red[2]+red[3];
        ss = red[4]+red[5]+red[6]+red[7];
        float mu   = s * (1.0f/1024.0f);
        float rstd = rsqrtf(ss * (1.0f/1024.0f) - mu*mu + 1e-5f);
        float4 wv = *(const float4*)(w  + t*4);
        float4 bv = *(const float4*)(bb + t*4);
        xs[r*D_DIM + t*4+0] = (vv.x-mu)*rstd*wv.x + bv.x;
        xs[r*D_DIM + t*4+1] = (vv.y-mu)*rstd*wv.y + bv.y;
        xs[r*D_DIM + t*4+2] = (vv.z-mu)*rstd*wv.z + bv.z;
        xs[r*D_DIM + t*4+3] = (vv.w-mu)*rstd*wv.w + bv.w;
        __syncthreads();
    }
    int vrow = blockIdx.x * 4 + wid;
    float s0 = 0.f, s1 = 0.f;
#pragma unroll
    for (int it=0; it<4; it++){
        int j = it*64 + lane;
        float4 w4 = *(const float4*)(hw + (size_t)vrow * D_DIM + j*4);
        float4 x0 = *(const float4*)&xs[j*4];
        float4 x1 = *(const float4*)&xs[D_DIM + j*4];
        s0 += w4.x*x0.x + w4.y*x0.y + w4.z*x0.z + w4.w*x0.w;
        s1 += w4.x*x1.x + w4.y*x1.y + w4.z*x1.z + w4.w*x1.w;
    }
#pragma unroll
    for (int off=1; off<64; off<<=1){
        s0 += __shfl_xor(s0, off);
        s1 += __shfl_xor(s1, off);
    }
    if (lane == 0){
        out[vrow]          = s0;
        out[V_SIZE + vrow] = s1;
    }
}

// ---------------------------------------------------------------------------
extern "C" void kernel_launch(void* const* d_in, const int* in_sizes, int n_in,
                              void* d_out, int out_size, void* d_ws, size_t ws_size,
                              hipStream_t stream)
{
    (void)in_sizes; (void)n_in; (void)out_size; (void)ws_size;
    const int*   ids  = (const int*)  d_in[0];
    const float* tok  = (const float*)d_in[1];
    const float* pos  = (const float*)d_in[2];
    const float* ln1w = (const float*)d_in[3];
    const float* ln1b = (const float*)d_in[4];
    const float* ln2w = (const float*)d_in[5];
    const float* ln2b = (const float*)d_in[6];
    const float* qw   = (const float*)d_in[7];
    const float* qbi  = (const float*)d_in[8];
    const float* kw   = (const float*)d_in[9];
    const float* kbi  = (const float*)d_in[10];
    const float* vw   = (const float*)d_in[11];
    const float* vbi  = (const float*)d_in[12];
    const float* ow   = (const float*)d_in[13];
    const float* obi  = (const float*)d_in[14];
    const float* f1w  = (const float*)d_in[15];
    const float* f1b  = (const float*)d_in[16];
    const float* f2w  = (const float*)d_in[17];
    const float* f2b  = (const float*)d_in[18];
    const float* lnfw = (const float*)d_in[19];
    const float* lnfb = (const float*)d_in[20];
    const float* hw   = (const float*)d_in[21];

    const long MD = (long)1024*1024;          // D*D elems
    char* p = (char*)d_ws;
    float* x    = (float*)p; p += (size_t)M_ROWS * D_DIM * 4;
    u16* h      = (u16*)p;   p += (size_t)M_ROWS * D_DIM * 2;
    u16* qkvbuf = (u16*)p;   p += (size_t)M_ROWS * 3072 * 2;
    u16* ybuf   = (u16*)p;   p += (size_t)M_ROWS * D_DIM * 2;
    u16* h1     = (u16*)p;   p += (size_t)M_ROWS * FF_DIM * 2;
    u16* part   = (u16*)p;   p += (size_t)KSPL * M_ROWS * D_DIM * 2;
    u16* wbuf   = (u16*)p;   p += (size_t)48 * MD * 2;
    // 2-row tail buffers
    u16*   q2   = (u16*)p;   p += 2 * D_DIM * 2;
    float* x2   = (float*)p; p += 2 * D_DIM * 4;
    float* x3   = (float*)p; p += 2 * D_DIM * 4;
    u16*   g2   = (u16*)p;   p += 2 * FF_DIM * 2;
    float* Yp   = (float*)p; p += 4 * 32 * 64 * 4;
    float* psp  = (float*)p; p += 4 * 32 * 4;
    float* logits = (float*)d_out;

    u16* w_qkv = wbuf;                  // [L][3072][1024]  (q|k|v)
    u16* w_o   = wbuf + 12*MD;          // [L][1024][1024]
    u16* w_f1  = wbuf + 16*MD;          // [L][4096][1024]
    u16* w_f2  = wbuf + 32*MD;          // [L][1024][4096]

    cvt_all_k<<<dim3(12288), 256, 0, stream>>>(
        qw, kw, vw, ow, f1w, f2w, w_qkv, w_o, w_f1, w_f2);

    embed_ln_k<<<dim3(M_ROWS), 256, 0, stream>>>(ids, tok, pos, ln1w, ln1b, x, h);

    for (int i = 0; i < L_LAYERS - 1; i++){
        gemm64o_k<0><<<dim3(32, 24), 256, 0, stream>>>(
            h, w_qkv + (size_t)i*3*MD,
            qbi + i*D_DIM, kbi + i*D_DIM, vbi + i*D_DIM,
            qkvbuf, 3072, D_DIM);
        attn_k<<<dim3(8, 32), 512, 0, stream>>>(qkvbuf, ybuf);
        gemm64_k<<<dim3(32, 8, KSPL), 256, 0, stream>>>(
            ybuf, w_o + (size_t)i*MD, part, D_DIM, D_DIM, D_DIM/KSPL);
        reduce_ln_k<<<dim3(M_ROWS), 256, 0, stream>>>(
            part, obi + i*D_DIM, x, ln2w + i*D_DIM, ln2b + i*D_DIM, h);
        gemm_fc1_k<<<dim3(16, 32), 256, 0, stream>>>(
            h, w_f1 + (size_t)i*4*MD, f1b + i*FF_DIM, h1, FF_DIM, D_DIM);
        gemm64_k<<<dim3(32, 8, KSPL), 256, 0, stream>>>(
            h1, w_f2 + (size_t)i*4*MD, part, D_DIM, FF_DIM, FF_DIM/KSPL);
        reduce_ln_k<<<dim3(M_ROWS), 256, 0, stream>>>(
            part, f2b + i*D_DIM, x, ln1w + (i+1)*D_DIM, ln1b + (i+1)*D_DIM, h);
    }

    // ---- last layer: K|V GEMM (N=2048) + 2-row tail ----
    const int L3 = L_LAYERS - 1;
    gemm64o_k<-1><<<dim3(32, 16), 256, 0, stream>>>(
        h, w_qkv + (size_t)L3*3*MD + MD,          // k rows then v rows
        kbi + L3*D_DIM, vbi + L3*D_DIM, vbi + L3*D_DIM,
        qkvbuf, 2048, D_DIM);
    // q for the 2 live rows
    rowpair_k<3><<<dim3(256), 256, 0, stream>>>(
        h + (size_t)(S_SEQ-1)*D_DIM, h + (size_t)(2*S_SEQ-1)*D_DIM,
        nullptr, nullptr, nullptr, nullptr, nullptr,
        w_qkv + (size_t)L3*3*MD, qbi + L3*D_DIM, nullptr,
        nullptr, q2, D_DIM, D_DIM);
    attn_last_k<<<dim3(4, 32), 256, 0, stream>>>(q2, qkvbuf, Yp, psp);
    rowpair_k<0><<<dim3(256), 256, 0, stream>>>(
        nullptr, nullptr, Yp, psp, nullptr, nullptr, nullptr,
        w_o + (size_t)L3*MD, obi + L3*D_DIM, x,
        x2, nullptr, D_DIM, D_DIM);
    rowpair_k<1><<<dim3(256), 256, 0, stream>>>(
        nullptr, nullptr, nullptr, nullptr, x2,
        ln2w + L3*D_DIM, ln2b + L3*D_DIM,
        w_f1 + (size_t)L3*4*MD, f1b + L3*FF_DIM, nullptr,
        nullptr, g2, FF_DIM, D_DIM);
    rowpair_k<2><<<dim3(256), 256, 0, stream>>>(
        g2, g2 + FF_DIM, nullptr, nullptr, x2, nullptr, nullptr,
        w_f2 + (size_t)L3*4*MD, f2b + L3*D_DIM, nullptr,
        x3, nullptr, D_DIM, FF_DIM);
    head_ln_k<<<dim3(V_SIZE/4), 256, 0, stream>>>(x3, lnfw, lnfb, hw, logits);
}

// Round 17
// 529.053 us; speedup vs baseline: 1.0605x; 1.0605x over previous
//
#include <hip/hip_runtime.h>

#define V_SIZE 32000
#define D_DIM  1024
#define H_HEADS 16
#define L_LAYERS 4
#define HD_DIM 64
#define FF_DIM 4096
#define B_BATCH 2
#define S_SEQ  1024
#define M_ROWS (B_BATCH*S_SEQ)
#define KSPL   2

typedef short  s16x8 __attribute__((ext_vector_type(8)));
typedef unsigned short u16x8 __attribute__((ext_vector_type(8)));
typedef float  f32x4 __attribute__((ext_vector_type(4)));
typedef unsigned short u16;
typedef unsigned int   u32;

// f32 -> bf16 round-to-nearest-even
__device__ inline u16 f2bf(float f){
    u32 u = __float_as_uint(f);
    return (u16)((u + 0x7FFFu + ((u >> 16) & 1u)) >> 16);
}
__device__ inline float b2f(u32 v){ return __uint_as_float(v << 16); }

// fast exact-enough GELU: sigmoid form; |err| <= ~4e-4
__device__ inline float gelu_f(float v){
    float y = 0.7978845608f * (v + 0.044715f*v*v*v);
    y = fmaxf(-15.f, fminf(15.f, y));
    float u = __expf(-2.f*y);
    return v / (1.f + u);
}

// Swizzled LDS address for 128-byte rows (64 bf16): byte ^= ((row&7)<<4)  [guide G4]
__device__ inline char* lds_swz(void* base, int row, int byteoff){
    return (char*)base + row*128 + (byteoff ^ ((row & 7) << 4));
}

// async global->LDS, 16B per lane. LDS dest must be linear-in-lane. [guide §5]
__device__ inline void gload16(const u16* g, u16* l){
    __builtin_amdgcn_global_load_lds(
        (const __attribute__((address_space(1))) void*)g,
        (__attribute__((address_space(3))) void*)l, 16, 0, 0);
}

// Matching global source column for swizzled LDS slot 'lin' (16B granules):
__device__ inline int swz_src_col(int lin){
    int row = lin >> 3, s8 = lin & 7;
    return (s8*8) ^ ((row & 7) << 3);
}

__device__ inline s16x8 cvt8(float4 a, float4 b){
    s16x8 o;
    o[0]=(short)f2bf(a.x); o[1]=(short)f2bf(a.y);
    o[2]=(short)f2bf(a.z); o[3]=(short)f2bf(a.w);
    o[4]=(short)f2bf(b.x); o[5]=(short)f2bf(b.y);
    o[6]=(short)f2bf(b.z); o[7]=(short)f2bf(b.w);
    return o;
}

// ---------------------------------------------------------------------------
// All weight converts in ONE dispatch (frozen at r14 config: regular
// cached loads/stores. r16 A/B showed nontemporal hurts -31us net:
// cache-resident weights benefit the downstream layer-0 GEMMs).
// ---------------------------------------------------------------------------
__global__ __launch_bounds__(256) void cvt_all_k(
    const float* __restrict__ qw, const float* __restrict__ kw,
    const float* __restrict__ vw, const float* __restrict__ ow,
    const float* __restrict__ f1w, const float* __restrict__ f2w,
    u16* __restrict__ w_qkv, u16* __restrict__ w_o,
    u16* __restrict__ w_f1, u16* __restrict__ w_f2)
{
    const long M1 = 1L << 20;
    const int bx = blockIdx.x;
    const float* s; u16* d; long base;
    if (bx < 3072){
        int which = bx >> 10;
        s = (which==0) ? qw : ((which==1) ? kw : vw);
        base = (long)(bx & 1023) * 4096;
        long layer = base >> 20, rem = base & (M1 - 1);
        d = w_qkv + layer*3*M1 + which*M1 + rem;
        s += base;
    } else if (bx < 4096){
        base = (long)(bx - 3072) * 4096; s = ow  + base; d = w_o  + base;
    } else if (bx < 8192){
        base = (long)(bx - 4096) * 4096; s = f1w + base; d = w_f1 + base;
    } else {
        base = (long)(bx - 8192) * 4096; s = f2w + base; d = w_f2 + base;
    }
    const int t8 = threadIdx.x * 8;
#pragma unroll
    for (int j = 0; j < 2; j++){
        const float* sp = s + j*2048 + t8;
        float4 v0 = *(const float4*)(sp);
        float4 v1 = *(const float4*)(sp + 4);
        *(s16x8*)(d + j*2048 + t8) = cvt8(v0, v1);
    }
}

// ---------------------------------------------------------------------------
// Embedding + LN1(layer0): block = one row.
// ---------------------------------------------------------------------------
__global__ __launch_bounds__(256) void embed_ln_k(
    const int* __restrict__ ids, const float* __restrict__ tok,
    const float* __restrict__ pos, const float* __restrict__ lw,
    const float* __restrict__ lb, float* __restrict__ x, u16* __restrict__ h)
{
    int row = blockIdx.x;
    int id  = ids[row];
    int s   = row & (S_SEQ - 1);
    int t   = threadIdx.x;
    float4 tv = *(const float4*)(tok + (size_t)id * D_DIM + t*4);
    float4 pv = *(const float4*)(pos + (size_t)s  * D_DIM + t*4);
    float4 vv;
    vv.x = tv.x + pv.x; vv.y = tv.y + pv.y; vv.z = tv.z + pv.z; vv.w = tv.w + pv.w;
    *(float4*)(x + (size_t)row * D_DIM + t*4) = vv;
    float sm  = vv.x + vv.y + vv.z + vv.w;
    float ss = vv.x*vv.x + vv.y*vv.y + vv.z*vv.z + vv.w*vv.w;
#pragma unroll
    for (int off = 1; off < 64; off <<= 1){
        sm += __shfl_xor(sm, off);
        ss += __shfl_xor(ss, off);
    }
    __shared__ float red[8];
    const int wid = t >> 6, lane = t & 63;
    if (lane == 0){ red[wid] = sm; red[4 + wid] = ss; }
    __syncthreads();
    sm = red[0] + red[1] + red[2] + red[3];
    ss = red[4] + red[5] + red[6] + red[7];
    float mu   = sm * (1.0f/1024.0f);
    float rstd = rsqrtf(ss * (1.0f/1024.0f) - mu*mu + 1e-5f);
    float4 wv = *(const float4*)(lw + t*4);
    float4 bv = *(const float4*)(lb + t*4);
    uint2 pk;
    pk.x = (u32)f2bf((vv.x-mu)*rstd*wv.x + bv.x) | ((u32)f2bf((vv.y-mu)*rstd*wv.y + bv.y) << 16);
    pk.y = (u32)f2bf((vv.z-mu)*rstd*wv.z + bv.z) | ((u32)f2bf((vv.w-mu)*rstd*wv.w + bv.w) << 16);
    *(uint2*)(h + (size_t)row * D_DIM + t*4) = pk;
}

// ---------------------------------------------------------------------------
// Split-K reduce (bf16 partials) + residual + fused LN. Block = row.
// ---------------------------------------------------------------------------
__global__ __launch_bounds__(256) void reduce_ln_k(
    const u16* __restrict__ part, const float* __restrict__ bias,
    float* __restrict__ x,
    const float* __restrict__ lw, const float* __restrict__ lb,
    u16* __restrict__ h)
{
    const int row = blockIdx.x, t = threadIdx.x;
    const size_t off = (size_t)row * D_DIM + t*4;
    float4 a = *(float4*)(x + off);
    float4 bv = *(const float4*)(bias + t*4);
    a.x += bv.x; a.y += bv.y; a.z += bv.z; a.w += bv.w;
#pragma unroll
    for (int si = 0; si < KSPL; si++){
        uint2 pv = *(const uint2*)(part + (size_t)si * M_ROWS * D_DIM + off);
        a.x += b2f(pv.x & 0xffffu); a.y += b2f(pv.x >> 16);
        a.z += b2f(pv.y & 0xffffu); a.w += b2f(pv.y >> 16);
    }
    *(float4*)(x + off) = a;
    float sm = a.x + a.y + a.z + a.w;
    float ss = a.x*a.x + a.y*a.y + a.z*a.z + a.w*a.w;
#pragma unroll
    for (int o2 = 1; o2 < 64; o2 <<= 1){
        sm += __shfl_xor(sm, o2);
        ss += __shfl_xor(ss, o2);
    }
    __shared__ float red[8];
    const int wid = t >> 6, lane = t & 63;
    if (lane == 0){ red[wid] = sm; red[4 + wid] = ss; }
    __syncthreads();
    sm = red[0] + red[1] + red[2] + red[3];
    ss = red[4] + red[5] + red[6] + red[7];
    float mu   = sm * (1.0f/1024.0f);
    float rstd = rsqrtf(ss * (1.0f/1024.0f) - mu*mu + 1e-5f);
    float4 wv = *(const float4*)(lw + t*4);
    float4 lbv = *(const float4*)(lb + t*4);
    uint2 pk;
    pk.x = (u32)f2bf((a.x-mu)*rstd*wv.x + lbv.x) | ((u32)f2bf((a.y-mu)*rstd*wv.y + lbv.y) << 16);
    pk.y = (u32)f2bf((a.z-mu)*rstd*wv.z + lbv.z) | ((u32)f2bf((a.w-mu)*rstd*wv.w + lbv.w) << 16);
    *(uint2*)(h + (size_t)row * D_DIM + t*4) = pk;
}

// ---------------------------------------------------------------------------
// fc1 GEMM: 128x128 tile, bias + gelu -> bf16. grid (16,32), 2 blocks/CU.
// ---------------------------------------------------------------------------
__global__ __launch_bounds__(256) void gemm_fc1_k(
    const u16* __restrict__ A, const u16* __restrict__ Bw,
    const float* __restrict__ b0, u16* __restrict__ outB, int Ndim, int Kdim)
{
    const int nx = gridDim.x, ny = gridDim.y;
    const int nwg = nx*ny;
    int orig = blockIdx.y*nx + blockIdx.x;
    int wg = (orig & 7)*(nwg >> 3) + (orig >> 3);
    const int bm = wg % nx;
    const int bn = wg / nx;

    const int nk = Kdim >> 6;

    __shared__ __align__(16) u16 As[2][128*64];
    __shared__ __align__(16) u16 Bs[2][128*64];

    const int t = threadIdx.x;
    const int wid = t >> 6, lane = t & 63, lr = lane & 15, lg = lane >> 4;
    const int wr = wid >> 1, wc = wid & 1;

    f32x4 acc[4][4];
#pragma unroll
    for (int m=0;m<4;m++)
#pragma unroll
        for (int n=0;n<4;n++) acc[m][n] = (f32x4){0.f,0.f,0.f,0.f};

    const u16* Abase = A  + (size_t)(bm*128)*Kdim;
    const u16* Bbase = Bw + (size_t)(bn*128)*Kdim;

    auto stage = [&](int koff, int buf){
#pragma unroll
        for (int i=0;i<4;i++){
            int lin = i*256 + t;
            int row = lin >> 3;
            int sc  = swz_src_col(lin);
            gload16(Abase + (size_t)row*Kdim + koff + sc, &As[buf][lin*8]);
        }
#pragma unroll
        for (int i=0;i<4;i++){
            int lin = i*256 + t;
            int row = lin >> 3;
            int sc  = swz_src_col(lin);
            gload16(Bbase + (size_t)row*Kdim + koff + sc, &Bs[buf][lin*8]);
        }
    };

    stage(0, 0);
    __syncthreads();
    int cb = 0;
    for (int ki = 0; ki < nk; ki++){
        if (ki+1 < nk) stage((ki+1)*64, cb^1);
#pragma unroll
        for (int kk=0;kk<2;kk++){
            s16x8 a[4], b[4];
#pragma unroll
            for (int m=0;m<4;m++)
                a[m] = *(s16x8*)lds_swz(As[cb], wr*64 + m*16 + lr, kk*64 + lg*16);
#pragma unroll
            for (int n=0;n<4;n++)
                b[n] = *(s16x8*)lds_swz(Bs[cb], wc*64 + n*16 + lr, kk*64 + lg*16);
#pragma unroll
            for (int m=0;m<4;m++)
#pragma unroll
                for (int n=0;n<4;n++)
                    acc[m][n] = __builtin_amdgcn_mfma_f32_16x16x32_bf16(a[m], b[n], acc[m][n], 0, 0, 0);
        }
        __syncthreads();
        cb ^= 1;
    }

#pragma unroll
    for (int n=0;n<4;n++){
        int col = bn*128 + wc*64 + n*16 + lr;
        float bvv = b0[col];
#pragma unroll
        for (int m=0;m<4;m++){
            int row0 = bm*128 + wr*64 + m*16 + lg*4;
#pragma unroll
            for (int j=0;j<4;j++){
                int row = row0 + j;
                float val = gelu_f(acc[m][n][j] + bvv);
                outB[(size_t)row * Ndim + col] = f2bf(val);
            }
        }
    }
}

// ---------------------------------------------------------------------------
// Output GEMM, 64x128 tile: C = A @ Bw^T + bias -> bf16.
// Segmented bias (col>>10 -> b0/b1/b2), segment QSEG scaled 0.125.
// ---------------------------------------------------------------------------
template<int QSEG>
__global__ __launch_bounds__(256) void gemm64o_k(
    const u16* __restrict__ A, const u16* __restrict__ Bw,
    const float* __restrict__ b0, const float* __restrict__ b1, const float* __restrict__ b2,
    u16* __restrict__ outB, int Ndim, int Kdim)
{
    const int nx = gridDim.x, ny = gridDim.y;
    const int nwg = nx*ny;
    int orig = blockIdx.y*nx + blockIdx.x;
    int wg = (orig & 7)*(nwg >> 3) + (orig >> 3);
    const int bm = wg % nx;
    const int bn = wg / nx;
    const int nk = Kdim >> 6;

    __shared__ __align__(16) u16 As[2][64*64];
    __shared__ __align__(16) u16 Bs[2][128*64];

    const int t = threadIdx.x;
    const int wid = t >> 6, lane = t & 63, lr = lane & 15, lg = lane >> 4;
    const int wr = wid >> 1, wc = wid & 1;

    f32x4 acc[2][4];
#pragma unroll
    for (int m=0;m<2;m++)
#pragma unroll
        for (int n=0;n<4;n++) acc[m][n] = (f32x4){0.f,0.f,0.f,0.f};

    const u16* Abase = A  + (size_t)(bm*64)*Kdim;
    const u16* Bbase = Bw + (size_t)(bn*128)*Kdim;

    auto stage = [&](int koff, int buf){
#pragma unroll
        for (int i=0;i<2;i++){
            int lin = i*256 + t;
            int row = lin >> 3;
            int sc  = swz_src_col(lin);
            gload16(Abase + (size_t)row*Kdim + koff + sc, &As[buf][lin*8]);
        }
#pragma unroll
        for (int i=0;i<4;i++){
            int lin = i*256 + t;
            int row = lin >> 3;
            int sc  = swz_src_col(lin);
            gload16(Bbase + (size_t)row*Kdim + koff + sc, &Bs[buf][lin*8]);
        }
    };

    stage(0, 0);
    __syncthreads();
    int cb = 0;
    for (int ki = 0; ki < nk; ki++){
        if (ki+1 < nk) stage((ki+1)*64, cb^1);
#pragma unroll
        for (int kk=0;kk<2;kk++){
            s16x8 a[2], b[4];
#pragma unroll
            for (int m=0;m<2;m++)
                a[m] = *(s16x8*)lds_swz(As[cb], wr*32 + m*16 + lr, kk*64 + lg*16);
#pragma unroll
            for (int n=0;n<4;n++)
                b[n] = *(s16x8*)lds_swz(Bs[cb], wc*64 + n*16 + lr, kk*64 + lg*16);
#pragma unroll
            for (int m=0;m<2;m++)
#pragma unroll
                for (int n=0;n<4;n++)
                    acc[m][n] = __builtin_amdgcn_mfma_f32_16x16x32_bf16(a[m], b[n], acc[m][n], 0, 0, 0);
        }
        __syncthreads();
        cb ^= 1;
    }

#pragma unroll
    for (int n=0;n<4;n++){
        int col = bn*128 + wc*64 + n*16 + lr;
        int which = col >> 10;
        const float* bp = (which==0) ? b0 : ((which==1) ? b1 : b2);
        float bvv = bp[col & 1023];
        float scl = (which == QSEG) ? 0.125f : 1.0f;
#pragma unroll
        for (int m=0;m<2;m++){
            int row0 = bm*64 + wr*32 + m*16 + lg*4;
#pragma unroll
            for (int j=0;j<4;j++){
                int row = row0 + j;
                float val = (acc[m][n][j] + bvv) * scl;
                outB[(size_t)row * Ndim + col] = f2bf(val);
            }
        }
    }
}

// ---------------------------------------------------------------------------
// Split-K GEMM, 64x128 tile: part[z] = A[M,K] @ Bw[N,K]^T  (K-slice z), bf16 out.
// ---------------------------------------------------------------------------
__global__ __launch_bounds__(256) void gemm64_k(
    const u16* __restrict__ A, const u16* __restrict__ Bw,
    u16* __restrict__ outP, int Ndim, int Kdim, int kper)
{
    const int nx = gridDim.x, ny = gridDim.y;
    const int nwg = nx*ny*gridDim.z;
    int orig = (blockIdx.z*ny + blockIdx.y)*nx + blockIdx.x;
    int wg = (orig & 7)*(nwg >> 3) + (orig >> 3);
    const int bm = wg % nx; wg /= nx;
    const int bn = wg % ny;
    const int z  = wg / ny;
    const int kbeg = z * kper;
    const int nk = kper >> 6;

    __shared__ __align__(16) u16 As[2][64*64];
    __shared__ __align__(16) u16 Bs[2][128*64];

    const int t = threadIdx.x;
    const int wid = t >> 6, lane = t & 63, lr = lane & 15, lg = lane >> 4;
    const int wr = wid >> 1, wc = wid & 1;

    f32x4 acc[2][4];
#pragma unroll
    for (int m=0;m<2;m++)
#pragma unroll
        for (int n=0;n<4;n++) acc[m][n] = (f32x4){0.f,0.f,0.f,0.f};

    const u16* Abase = A  + (size_t)(bm*64)*Kdim + kbeg;
    const u16* Bbase = Bw + (size_t)(bn*128)*Kdim + kbeg;

    auto stage = [&](int koff, int buf){
#pragma unroll
        for (int i=0;i<2;i++){
            int lin = i*256 + t;
            int row = lin >> 3;
            int sc  = swz_src_col(lin);
            gload16(Abase + (size_t)row*Kdim + koff + sc, &As[buf][lin*8]);
        }
#pragma unroll
        for (int i=0;i<4;i++){
            int lin = i*256 + t;
            int row = lin >> 3;
            int sc  = swz_src_col(lin);
            gload16(Bbase + (size_t)row*Kdim + koff + sc, &Bs[buf][lin*8]);
        }
    };

    stage(0, 0);
    __syncthreads();
    int cb = 0;
    for (int ki = 0; ki < nk; ki++){
        if (ki+1 < nk) stage((ki+1)*64, cb^1);
#pragma unroll
        for (int kk=0;kk<2;kk++){
            s16x8 a[2], b[4];
#pragma unroll
            for (int m=0;m<2;m++)
                a[m] = *(s16x8*)lds_swz(As[cb], wr*32 + m*16 + lr, kk*64 + lg*16);
#pragma unroll
            for (int n=0;n<4;n++)
                b[n] = *(s16x8*)lds_swz(Bs[cb], wc*64 + n*16 + lr, kk*64 + lg*16);
#pragma unroll
            for (int m=0;m<2;m++)
#pragma unroll
                for (int n=0;n<4;n++)
                    acc[m][n] = __builtin_amdgcn_mfma_f32_16x16x32_bf16(a[m], b[n], acc[m][n], 0, 0, 0);
        }
        __syncthreads();
        cb ^= 1;
    }

#pragma unroll
    for (int n=0;n<4;n++){
        int col = bn*128 + wc*64 + n*16 + lr;
#pragma unroll
        for (int m=0;m<2;m++){
            int row0 = bm*64 + wr*32 + m*16 + lg*4;
#pragma unroll
            for (int j=0;j<4;j++){
                int row = row0 + j;
                outP[(size_t)z * M_ROWS * Ndim + (size_t)row * Ndim + col] = f2bf(acc[m][n][j]);
            }
        }
    }
}

// ---------------------------------------------------------------------------
// Flash attention, causal, paired strips SHARING K/V tiles, 8 WAVES (512 thr).
// grid (8, B*H) = 256 blocks; waves 0-3: strip_lo, waves 4-7: strip_hi.
// ---------------------------------------------------------------------------
__global__ __launch_bounds__(512) void attn_k(
    const u16* __restrict__ qkv, u16* __restrict__ y)
{
    const int gx = gridDim.x;
    const int nwg = gx * gridDim.y;
    int orig = blockIdx.y*gx + blockIdx.x;
    int wg = (orig & 7)*(nwg >> 3) + (orig >> 3);
    const int p  = wg % gx;
    const int bh = wg / gx;
    const int b  = bh >> 4, h = bh & 15;

    const int s_lo = p, s_hi = 15 - p;
    const int ntiles = s_hi + 1;

    __shared__ __align__(16) u16 Ks[2][64*64];
    __shared__ __align__(16) u16 VTs[2][64*64];
    __shared__ __align__(16) u16 Ps[8][16*64];

    const int t = threadIdx.x, wid = t >> 6, lane = t & 63, lr = lane & 15, lg = lane >> 4;
    const size_t rowb = (size_t)b * S_SEQ;
    const u16* qp = qkv + h*HD_DIM;
    const u16* kp = qkv + 1024 + h*HD_DIM;
    const u16* vp = qkv + 2048 + h*HD_DIM;

    const int s  = (wid >= 4) ? s_hi : s_lo;
    const int wq = wid & 3;
    const int qw = s*64 + wq*16;

    s16x8 aq[2];
#pragma unroll
    for (int kc=0;kc<2;kc++)
        aq[kc] = *(const s16x8*)(qp + (rowb + qw + lr) * 3072 + kc*32 + lg*8);

    f32x4 o[4];
#pragma unroll
    for (int n=0;n<4;n++) o[n] = (f32x4){0.f,0.f,0.f,0.f};
    float lsum[4] = {0.f,0.f,0.f,0.f};

    const int kpr = t >> 3, dsl = t & 7;
    u16x8 vr0, vr1;

    auto issueK = [&](int kt, int buf){
        if (t >= 256){
#pragma unroll
            for (int i=0;i<2;i++){
                int lin = i*256 + (t - 256);
                int row = lin >> 3;
                int sc  = swz_src_col(lin);
                gload16(kp + (rowb + kt*64 + row)*3072 + sc, &Ks[buf][lin*8]);
            }
        }
    };
    auto loadV = [&](int kt){
        if (t < 256){
            vr0 = *(const u16x8*)(vp + (rowb + kt*64 + 2*kpr    )*3072 + dsl*8);
            vr1 = *(const u16x8*)(vp + (rowb + kt*64 + 2*kpr + 1)*3072 + dsl*8);
        }
    };
    auto writeVT = [&](int buf){
        if (t < 256){
#pragma unroll
            for (int j=0;j<8;j++){
                u32 pk = (u32)vr0[j] | ((u32)vr1[j] << 16);
                *(u32*)lds_swz(VTs[buf], dsl*8 + j, kpr*4) = pk;
            }
        }
    };

    auto doTile = [&](int kt, int cb){
        f32x4 sf[4];
#pragma unroll
        for (int n=0;n<4;n++) sf[n] = (f32x4){0.f,0.f,0.f,0.f};
        __builtin_amdgcn_s_setprio(1);
#pragma unroll
        for (int kc=0;kc<2;kc++){
#pragma unroll
            for (int n=0;n<4;n++){
                s16x8 bk = *(s16x8*)lds_swz(Ks[cb], n*16 + lr, kc*64 + lg*16);
                sf[n] = __builtin_amdgcn_mfma_f32_16x16x32_bf16(aq[kc], bk, sf[n], 0, 0, 0);
            }
        }
        __builtin_amdgcn_s_setprio(0);
        const bool diag = (kt == s);
        float rs[4] = {0.f,0.f,0.f,0.f};
#pragma unroll
        for (int n=0;n<4;n++){
            int key = kt*64 + n*16 + lr;
#pragma unroll
            for (int j=0;j<4;j++){
                float pe = __expf(sf[n][j]);
                if (diag && key > qw + lg*4 + j) pe = 0.f;
                sf[n][j] = pe; rs[j] += pe;
            }
        }
#pragma unroll
        for (int off=1; off<16; off<<=1){
#pragma unroll
            for (int j=0;j<4;j++) rs[j] += __shfl_xor(rs[j], off);
        }
#pragma unroll
        for (int j=0;j<4;j++) lsum[j] += rs[j];
        u16* Pw = Ps[wid];
#pragma unroll
        for (int n=0;n<4;n++)
#pragma unroll
            for (int j=0;j<4;j++)
                *(u16*)lds_swz(Pw, lg*4 + j, (n*16 + lr)*2) = f2bf(sf[n][j]);
        __builtin_amdgcn_s_setprio(1);
#pragma unroll
        for (int kc=0;kc<2;kc++){
            s16x8 pa = *(s16x8*)lds_swz(Pw, lr, kc*64 + lg*16);
#pragma unroll
            for (int n=0;n<4;n++){
                s16x8 bv = *(s16x8*)lds_swz(VTs[cb], n*16 + lr, kc*64 + lg*16);
                o[n] = __builtin_amdgcn_mfma_f32_16x16x32_bf16(pa, bv, o[n], 0, 0, 0);
            }
        }
        __builtin_amdgcn_s_setprio(0);
    };

    issueK(0, 0); loadV(0); writeVT(0);
    __syncthreads();
    int cb = 0;
    for (int kt = 0; kt < ntiles; kt++){
        const bool more = (kt+1 < ntiles);
        if (more){ issueK(kt+1, cb^1); loadV(kt+1); }

        if (kt <= s) doTile(kt, cb);

        if (more) writeVT(cb^1);
        __syncthreads();
        cb ^= 1;
    }

    float inv[4];
#pragma unroll
    for (int j=0;j<4;j++) inv[j] = 1.0f / lsum[j];
#pragma unroll
    for (int n=0;n<4;n++)
#pragma unroll
        for (int j=0;j<4;j++)
            y[(rowb + qw + lg*4 + j) * D_DIM + h*HD_DIM + n*16 + lr] = f2bf(o[n][j] * inv[j]);
}

// ---------------------------------------------------------------------------
// Last-layer attention: q-rows {1023,2047} only. kv: [B*S][2048] (k|v).
// ---------------------------------------------------------------------------
__global__ __launch_bounds__(256) void attn_last_k(
    const u16* __restrict__ q2, const u16* __restrict__ kv,
    float* __restrict__ Yp, float* __restrict__ psp)
{
    const int chunk = blockIdx.x;
    const int bh = blockIdx.y;
    const int b = bh >> 4, h = bh & 15;
    const int t = threadIdx.x;
    const size_t rowb = (size_t)b * S_SEQ;
    __shared__ float qs[64];
    __shared__ float ps[256];
    __shared__ float red[4];
    __shared__ float yred[4][64];
    if (t < 64) qs[t] = b2f(q2[b*1024 + h*HD_DIM + t]);
    __syncthreads();
    int k = chunk*256 + t;
    const u16* krow = kv + (rowb + k)*2048 + h*HD_DIM;
    float s = 0.f;
#pragma unroll
    for (int j=0;j<8;j++){
        u16x8 kv8 = *(const u16x8*)(krow + j*8);
#pragma unroll
        for (int e=0;e<8;e++) s += qs[j*8+e] * b2f((u32)(unsigned short)kv8[e]);
    }
    float p = __expf(s);
    ps[t] = p;
    float sp_ = p;
#pragma unroll
    for (int off=1; off<64; off<<=1) sp_ += __shfl_xor(sp_, off);
    if ((t & 63) == 0) red[t>>6] = sp_;
    __syncthreads();
    if (t == 0) psp[chunk*32 + bh] = red[0]+red[1]+red[2]+red[3];
    int d = t & 63, c = t >> 6;
    float acc = 0.f;
    const u16* vbase = kv + (rowb + chunk*256 + c*64)*2048 + 1024 + h*HD_DIM + d;
    for (int kk=0; kk<64; kk++)
        acc += ps[c*64 + kk] * b2f((u32)vbase[(size_t)kk*2048]);
    yred[c][d] = acc;
    __syncthreads();
    if (t < 64)
        Yp[(chunk*32 + bh)*64 + t] = yred[0][t]+yred[1][t]+yred[2][t]+yred[3][t];
}

// ---------------------------------------------------------------------------
// Two-row GEMM tail. grid = 256 blocks, 4 waves.
// ---------------------------------------------------------------------------
template<int MODE>
__global__ __launch_bounds__(256) void rowpair_k(
    const u16* __restrict__ A0, const u16* __restrict__ A1,
    const float* __restrict__ Yp, const float* __restrict__ psp,
    const float* __restrict__ x2in,
    const float* __restrict__ lw, const float* __restrict__ lb,
    const u16* __restrict__ W, const float* __restrict__ bias,
    const float* __restrict__ xresid,
    float* __restrict__ outF, u16* __restrict__ outB,
    int Ndim, int Kdim)
{
    __shared__ u16 As16[2][1024];
    __shared__ float red[8];
    const int t = threadIdx.x, wid = t >> 6, lane = t & 63;

    if (MODE == 0){
        for (int idx = t; idx < 2048; idx += 256){
            int r = idx >> 10, d10 = idx & 1023;
            int bh = r*16 + (d10 >> 6), d = d10 & 63;
            float psum = psp[bh] + psp[32+bh] + psp[64+bh] + psp[96+bh];
            float yv = Yp[bh*64+d] + Yp[(32+bh)*64+d] + Yp[(64+bh)*64+d] + Yp[(96+bh)*64+d];
            As16[r][d10] = f2bf(yv / psum);
        }
        __syncthreads();
    }
    if (MODE == 1){
#pragma unroll
        for (int r = 0; r < 2; r++){
            float4 vv = *(const float4*)(x2in + r*1024 + t*4);
            float sm = vv.x + vv.y + vv.z + vv.w;
            float ss = vv.x*vv.x + vv.y*vv.y + vv.z*vv.z + vv.w*vv.w;
#pragma unroll
            for (int o2 = 1; o2 < 64; o2 <<= 1){
                sm += __shfl_xor(sm, o2);
                ss += __shfl_xor(ss, o2);
            }
            if (lane == 0){ red[wid] = sm; red[4+wid] = ss; }
            __syncthreads();
            sm = red[0]+red[1]+red[2]+red[3];
            ss = red[4]+red[5]+red[6]+red[7];
            float mu = sm * (1.0f/1024.0f);
            float rstd = rsqrtf(ss * (1.0f/1024.0f) - mu*mu + 1e-5f);
            float4 wv  = *(const float4*)(lw + t*4);
            float4 lbv = *(const float4*)(lb + t*4);
            As16[r][t*4+0] = f2bf((vv.x-mu)*rstd*wv.x + lbv.x);
            As16[r][t*4+1] = f2bf((vv.y-mu)*rstd*wv.y + lbv.y);
            As16[r][t*4+2] = f2bf((vv.z-mu)*rstd*wv.z + lbv.z);
            As16[r][t*4+3] = f2bf((vv.w-mu)*rstd*wv.w + lbv.w);
            __syncthreads();
        }
    }

    const u16* pa0 = (MODE==0 || MODE==1) ? (const u16*)As16[0] : A0;
    const u16* pa1 = (MODE==0 || MODE==1) ? (const u16*)As16[1] : A1;

    const int colsPerBlock = Ndim >> 8;
    const int colsPerWave  = colsPerBlock >> 2;
    const int nj = Kdim >> 9;
    for (int cc = 0; cc < colsPerWave; cc++){
        int col = blockIdx.x * colsPerBlock + wid * colsPerWave + cc;
        const u16* wrow = W + (size_t)col * Kdim;
        float s0 = 0.f, s1 = 0.f;
        for (int j = 0; j < nj; j++){
            int k = j*512 + lane*8;
            u16x8 wv = *(const u16x8*)(wrow + k);
            u16x8 a0 = *(const u16x8*)(pa0 + k);
            u16x8 a1 = *(const u16x8*)(pa1 + k);
#pragma unroll
            for (int e=0;e<8;e++){
                float wf = b2f((u32)wv[e]);
                s0 += b2f((u32)a0[e]) * wf;
                s1 += b2f((u32)a1[e]) * wf;
            }
        }
#pragma unroll
        for (int off=1; off<64; off<<=1){
            s0 += __shfl_xor(s0, off);
            s1 += __shfl_xor(s1, off);
        }
        if (lane == 0){
            float bv = bias[col];
            if (MODE == 0){
                outF[col]         = xresid[(size_t)(S_SEQ-1)*D_DIM + col]   + bv + s0;
                outF[D_DIM + col] = xresid[(size_t)(2*S_SEQ-1)*D_DIM + col] + bv + s1;
            } else if (MODE == 1){
                outB[col]         = f2bf(gelu_f(s0 + bv));
                outB[Ndim + col]  = f2bf(gelu_f(s1 + bv));
            } else if (MODE == 2){
                outF[col]         = x2in[col]         + bv + s0;
                outF[D_DIM + col] = x2in[D_DIM + col] + bv + s1;
            } else {
                outB[col]         = f2bf((s0 + bv) * 0.125f);
                outB[Ndim + col]  = f2bf((s1 + bv) * 0.125f);
            }
        }
    }
}

// ---------------------------------------------------------------------------
// Head matvec with fused final LN: xs = LN(x3) per block, then dot rows.
// ---------------------------------------------------------------------------
__global__ __launch_bounds__(256) void head_ln_k(
    const float* __restrict__ x3, const float* __restrict__ w, const float* __restrict__ bb,
    const float* __restrict__ hw, float* __restrict__ out)
{
    __shared__ float xs[2*D_DIM];
    __shared__ float red[8];
    int t = threadIdx.x, wid = t >> 6, lane = t & 63;
#pragma unroll
    for (int r = 0; r < 2; r++){
        float4 vv = *(const float4*)(x3 + r*D_DIM + t*4);
        float s  = vv.x + vv.y + vv.z + vv.w;
        float ss = vv.x*vv.x + vv.y*vv.y + vv.z*vv.z + vv.w*vv.w;
#pragma unroll
        for (int off = 1; off < 64; off <<= 1){
            s  += __shfl_xor(s,  off);
            ss += __shfl_xor(ss, off);
        }
        if (lane == 0){ red[wid] = s; red[4+wid] = ss; }
        __syncthreads();
        s  = red[0]+red[1]+red[2]+red[3];
        ss = red[4]+red[5]+red[6]+red[7];
        float mu   = s * (1.0f/1024.0f);
        float rstd = rsqrtf(ss * (1.0f/1024.0f) - mu*mu + 1e-5f);
        float4 wv = *(const float4*)(w  + t*4);
        float4 bv = *(const float4*)(bb + t*4);
        xs[r*D_DIM + t*4+0] = (vv.x-mu)*rstd*wv.x + bv.x;
        xs[r*D_DIM + t*4+1] = (vv.y-mu)*rstd*wv.y + bv.y;
        xs[r*D_DIM + t*4+2] = (vv.z-mu)*rstd*wv.z + bv.z;
        xs[r*D_DIM + t*4+3] = (vv.w-mu)*rstd*wv.w + bv.w;
        __syncthreads();
    }
    int vrow = blockIdx.x * 4 + wid;
    float s0 = 0.f, s1 = 0.f;
#pragma unroll
    for (int it=0; it<4; it++){
        int j = it*64 + lane;
        float4 w4 = *(const float4*)(hw + (size_t)vrow * D_DIM + j*4);
        float4 x0 = *(const float4*)&xs[j*4];
        float4 x1 = *(const float4*)&xs[D_DIM + j*4];
        s0 += w4.x*x0.x + w4.y*x0.y + w4.z*x0.z + w4.w*x0.w;
        s1 += w4.x*x1.x + w4.y*x1.y + w4.z*x1.z + w4.w*x1.w;
    }
#pragma unroll
    for (int off=1; off<64; off<<=1){
        s0 += __shfl_xor(s0, off);
        s1 += __shfl_xor(s1, off);
    }
    if (lane == 0){
        out[vrow]          = s0;
        out[V_SIZE + vrow] = s1;
    }
}

// ---------------------------------------------------------------------------
extern "C" void kernel_launch(void* const* d_in, const int* in_sizes, int n_in,
                              void* d_out, int out_size, void* d_ws, size_t ws_size,
                              hipStream_t stream)
{
    (void)in_sizes; (void)n_in; (void)out_size; (void)ws_size;
    const int*   ids  = (const int*)  d_in[0];
    const float* tok  = (const float*)d_in[1];
    const float* pos  = (const float*)d_in[2];
    const float* ln1w = (const float*)d_in[3];
    const float* ln1b = (const float*)d_in[4];
    const float* ln2w = (const float*)d_in[5];
    const float* ln2b = (const float*)d_in[6];
    const float* qw   = (const float*)d_in[7];
    const float* qbi  = (const float*)d_in[8];
    const float* kw   = (const float*)d_in[9];
    const float* kbi  = (const float*)d_in[10];
    const float* vw   = (const float*)d_in[11];
    const float* vbi  = (const float*)d_in[12];
    const float* ow   = (const float*)d_in[13];
    const float* obi  = (const float*)d_in[14];
    const float* f1w  = (const float*)d_in[15];
    const float* f1b  = (const float*)d_in[16];
    const float* f2w  = (const float*)d_in[17];
    const float* f2b  = (const float*)d_in[18];
    const float* lnfw = (const float*)d_in[19];
    const float* lnfb = (const float*)d_in[20];
    const float* hw   = (const float*)d_in[21];

    const long MD = (long)1024*1024;          // D*D elems
    char* p = (char*)d_ws;
    float* x    = (float*)p; p += (size_t)M_ROWS * D_DIM * 4;
    u16* h      = (u16*)p;   p += (size_t)M_ROWS * D_DIM * 2;
    u16* qkvbuf = (u16*)p;   p += (size_t)M_ROWS * 3072 * 2;
    u16* ybuf   = (u16*)p;   p += (size_t)M_ROWS * D_DIM * 2;
    u16* h1     = (u16*)p;   p += (size_t)M_ROWS * FF_DIM * 2;
    u16* part   = (u16*)p;   p += (size_t)KSPL * M_ROWS * D_DIM * 2;
    u16* wbuf   = (u16*)p;   p += (size_t)48 * MD * 2;
    // 2-row tail buffers
    u16*   q2   = (u16*)p;   p += 2 * D_DIM * 2;
    float* x2   = (float*)p; p += 2 * D_DIM * 4;
    float* x3   = (float*)p; p += 2 * D_DIM * 4;
    u16*   g2   = (u16*)p;   p += 2 * FF_DIM * 2;
    float* Yp   = (float*)p; p += 4 * 32 * 64 * 4;
    float* psp  = (float*)p; p += 4 * 32 * 4;
    float* logits = (float*)d_out;

    u16* w_qkv = wbuf;                  // [L][3072][1024]  (q|k|v)
    u16* w_o   = wbuf + 12*MD;          // [L][1024][1024]
    u16* w_f1  = wbuf + 16*MD;          // [L][4096][1024]
    u16* w_f2  = wbuf + 32*MD;          // [L][1024][4096]

    cvt_all_k<<<dim3(12288), 256, 0, stream>>>(
        qw, kw, vw, ow, f1w, f2w, w_qkv, w_o, w_f1, w_f2);

    embed_ln_k<<<dim3(M_ROWS), 256, 0, stream>>>(ids, tok, pos, ln1w, ln1b, x, h);

    for (int i = 0; i < L_LAYERS - 1; i++){
        gemm64o_k<0><<<dim3(32, 24), 256, 0, stream>>>(
            h, w_qkv + (size_t)i*3*MD,
            qbi + i*D_DIM, kbi + i*D_DIM, vbi + i*D_DIM,
            qkvbuf, 3072, D_DIM);
        attn_k<<<dim3(8, 32), 512, 0, stream>>>(qkvbuf, ybuf);
        gemm64_k<<<dim3(32, 8, KSPL), 256, 0, stream>>>(
            ybuf, w_o + (size_t)i*MD, part, D_DIM, D_DIM, D_DIM/KSPL);
        reduce_ln_k<<<dim3(M_ROWS), 256, 0, stream>>>(
            part, obi + i*D_DIM, x, ln2w + i*D_DIM, ln2b + i*D_DIM, h);
        gemm_fc1_k<<<dim3(16, 32), 256, 0, stream>>>(
            h, w_f1 + (size_t)i*4*MD, f1b + i*FF_DIM, h1, FF_DIM, D_DIM);
        gemm64_k<<<dim3(32, 8, KSPL), 256, 0, stream>>>(
            h1, w_f2 + (size_t)i*4*MD, part, D_DIM, FF_DIM, FF_DIM/KSPL);
        reduce_ln_k<<<dim3(M_ROWS), 256, 0, stream>>>(
            part, f2b + i*D_DIM, x, ln1w + (i+1)*D_DIM, ln1b + (i+1)*D_DIM, h);
    }

    // ---- last layer: K|V GEMM (N=2048) + 2-row tail ----
    const int L3 = L_LAYERS - 1;
    gemm64o_k<-1><<<dim3(32, 16), 256, 0, stream>>>(
        h, w_qkv + (size_t)L3*3*MD + MD,          // k rows then v rows
        kbi + L3*D_DIM, vbi + L3*D_DIM, vbi + L3*D_DIM,
        qkvbuf, 2048, D_DIM);
    // q for the 2 live rows
    rowpair_k<3><<<dim3(256), 256, 0, stream>>>(
        h + (size_t)(S_SEQ-1)*D_DIM, h + (size_t)(2*S_SEQ-1)*D_DIM,
        nullptr, nullptr, nullptr, nullptr, nullptr,
        w_qkv + (size_t)L3*3*MD, qbi + L3*D_DIM, nullptr,
        nullptr, q2, D_DIM, D_DIM);
    attn_last_k<<<dim3(4, 32), 256, 0, stream>>>(q2, qkvbuf, Yp, psp);
    rowpair_k<0><<<dim3(256), 256, 0, stream>>>(
        nullptr, nullptr, Yp, psp, nullptr, nullptr, nullptr,
        w_o + (size_t)L3*MD, obi + L3*D_DIM, x,
        x2, nullptr, D_DIM, D_DIM);
    rowpair_k<1><<<dim3(256), 256, 0, stream>>>(
        nullptr, nullptr, nullptr, nullptr, x2,
        ln2w + L3*D_DIM, ln2b + L3*D_DIM,
        w_f1 + (size_t)L3*4*MD, f1b + L3*FF_DIM, nullptr,
        nullptr, g2, FF_DIM, D_DIM);
    rowpair_k<2><<<dim3(256), 256, 0, stream>>>(
        g2, g2 + FF_DIM, nullptr, nullptr, x2, nullptr, nullptr,
        w_f2 + (size_t)L3*4*MD, f2b + L3*D_DIM, nullptr,
        x3, nullptr, D_DIM, FF_DIM);
    head_ln_k<<<dim3(V_SIZE/4), 256, 0, stream>>>(x3, lnfw, lnfb, hw, logits);
}